// Round 4
// baseline (588.750 us; speedup 1.0000x reference)
//
#include <hip/hip_runtime.h>

// Entmax-1.5 over last axis. tau* is the root of
//   f(tau) = sum_i max(x_i - tau, 0)^2 - 1   (convex, piecewise quadratic, decreasing)
// Piece-exact (Michelot-style) iteration with F = sum y^2, G = sum y, K = #{y>0}:
//   u = (F-1) / (G + sqrt(G^2 - K*(F-1))),  tau += u
//
// R3 key fact: tau stays in [-1, 0] for the entire iteration (tau0=-1; from-below
// steps land <= tau*; from-above steps solve a support-restricted quadratic q with
// q(-1) >= 1, so the root is >= -1). Hence elements with x <= -1 contribute ZERO
// to F,G,K at every iterate and to the output. For Gaussian rows + mask, only
// ~40-70 of 2048 elements survive x > -1 (~0.7 per lane). We compact up to 4
// candidates/lane into scalar regs (shift-queue of cndmasks, no dynamic indexing)
// and iterate over 4 values instead of 32 (~8x less VALU per iteration). Waves
// where any lane overflows 4 candidates (rare; also pathological near-uniform
// rows) take a wave-uniform fallback running the full 32-element scan — exact.
// One wave per row of S=2048; x[] stays in registers for the epilogue.

#define NEG_FILL (-1.0e4f)

static constexpr int S_DIM = 2048;
static constexpr int WAVES_PER_BLOCK = 4;       // 256-thread blocks
static constexpr int ELEMS = S_DIM / 64;        // 32 floats per lane
static constexpr int VEC = ELEMS / 4;           // 8 float4 loads per lane

__device__ __forceinline__ void wave_reduce3(float& F, float& G, float& K) {
#pragma unroll
    for (int off = 32; off >= 1; off >>= 1) {
        F += __shfl_xor(F, off, 64);
        G += __shfl_xor(G, off, 64);
        K += __shfl_xor(K, off, 64);
    }
}

__global__ __launch_bounds__(256) void entmax15_kernel(
    const float* __restrict__ scores,
    const int*   __restrict__ mask,
    float*       __restrict__ out,
    int nrows)
{
    const int lane = threadIdx.x & 63;
    const int wave = threadIdx.x >> 6;
    const int row  = blockIdx.x * WAVES_PER_BLOCK + wave;
    if (row >= nrows) return;

    const size_t base = (size_t)row * S_DIM;
    const float4* __restrict__ srow = (const float4*)(scores + base);
    const int4*   __restrict__ mrow = (const int4*)(mask + base);
    float4*       __restrict__ orow = (float4*)(out + base);

    // ---- load + mask + row max (in registers) ----
    float x[ELEMS];
    float rmax = -3.402823466e38f;
#pragma unroll
    for (int j = 0; j < VEC; ++j) {
        const float4 s = srow[lane + 64 * j];
        const int4   m = mrow[lane + 64 * j];
        float v0 = m.x ? s.x : NEG_FILL;
        float v1 = m.y ? s.y : NEG_FILL;
        float v2 = m.z ? s.z : NEG_FILL;
        float v3 = m.w ? s.w : NEG_FILL;
        x[4 * j + 0] = v0;
        x[4 * j + 1] = v1;
        x[4 * j + 2] = v2;
        x[4 * j + 3] = v3;
        rmax = fmaxf(rmax, fmaxf(fmaxf(v0, v1), fmaxf(v2, v3)));
    }
#pragma unroll
    for (int off = 32; off >= 1; off >>= 1)
        rmax = fmaxf(rmax, __shfl_xor(rmax, off, 64));

    // ---- transform x=(x-max)*0.5 (max -> 0, tau* in [-1,0)) + candidate extract ----
    // Shift-queue: newest candidate pushes c0, older shift toward c3 (and drop).
    // Sentinel -2: d = -2 - tau <= -1 < 0 for tau in [-1,0] -> contributes nothing.
    const float shift = -0.5f * rmax;
    float c0 = -2.0f, c1 = -2.0f, c2 = -2.0f, c3 = -2.0f;
    int cnt = 0;
#pragma unroll
    for (int i = 0; i < ELEMS; ++i) {
        float v = fmaf(0.5f, x[i], shift);
        x[i] = v;
        bool t = v > -1.0f;
        if (t) { c3 = c2; c2 = c1; c1 = c0; c0 = v; cnt++; }  // -> cndmask chain
    }

    const bool overflow = __ballot(cnt > 4) != 0ull;  // wave-uniform

    float tau = -1.0f;
    float Kprev = -1.0f;

    if (!overflow) {
        // ---- fast path: iterate on <=4 candidates per lane ----
#pragma unroll 1
        for (int it = 0; it < 10; ++it) {
            float d0 = c0 - tau, d1 = c1 - tau, d2 = c2 - tau, d3 = c3 - tau;
            float y0 = fmaxf(d0, 0.0f), y1 = fmaxf(d1, 0.0f);
            float y2 = fmaxf(d2, 0.0f), y3 = fmaxf(d3, 0.0f);
            float F = fmaf(y0, y0, fmaf(y1, y1, fmaf(y2, y2, y3 * y3)));
            float G = (y0 + y1) + (y2 + y3);
            float K = ((d0 > 0.0f ? 1.0f : 0.0f) + (d1 > 0.0f ? 1.0f : 0.0f))
                    + ((d2 > 0.0f ? 1.0f : 0.0f) + (d3 > 0.0f ? 1.0f : 0.0f));
            wave_reduce3(F, G, K);
            if (K == Kprev) break;   // support stabilized -> previous solve exact
            Kprev = K;
            const float c = F - 1.0f;
            const float disc = fmaf(G, G, -K * c);
            const float denom = (disc > 0.0f) ? (G + sqrtf(disc)) : (2.0f * G);
            const float u = c / denom;
            tau += u;
            if (!(fabsf(u) > 1e-6f)) break;
        }
    } else {
        // ---- fallback: full 32-element scan (exact, rare) ----
#pragma unroll 1
        for (int it = 0; it < 12; ++it) {
            float F = 0.0f, G = 0.0f, K = 0.0f;
#pragma unroll
            for (int i = 0; i < ELEMS; ++i) {
                float d = x[i] - tau;
                float y = fmaxf(d, 0.0f);
                F = fmaf(y, y, F);
                G += y;
                K += (d > 0.0f) ? 1.0f : 0.0f;
            }
            wave_reduce3(F, G, K);
            if (K == Kprev) break;
            Kprev = K;
            const float c = F - 1.0f;
            const float disc = fmaf(G, G, -K * c);
            const float denom = (disc > 0.0f) ? (G + sqrtf(disc)) : (2.0f * G);
            const float u = c / denom;
            tau += u;
            if (!(fabsf(u) > 1e-6f)) break;
        }
    }

    // ---- epilogue: p = max(x - tau, 0)^2, coalesced float4 stores ----
#pragma unroll
    for (int j = 0; j < VEC; ++j) {
        float y0 = fmaxf(x[4 * j + 0] - tau, 0.0f);
        float y1 = fmaxf(x[4 * j + 1] - tau, 0.0f);
        float y2 = fmaxf(x[4 * j + 2] - tau, 0.0f);
        float y3 = fmaxf(x[4 * j + 3] - tau, 0.0f);
        float4 o;
        o.x = y0 * y0;
        o.y = y1 * y1;
        o.z = y2 * y2;
        o.w = y3 * y3;
        orow[lane + 64 * j] = o;
    }
}

extern "C" void kernel_launch(void* const* d_in, const int* in_sizes, int n_in,
                              void* d_out, int out_size, void* d_ws, size_t ws_size,
                              hipStream_t stream) {
    const float* scores = (const float*)d_in[0];
    const int*   mask   = (const int*)d_in[1];
    float*       out    = (float*)d_out;

    const int nrows = in_sizes[0] / S_DIM;  // 32768
    const int grid  = (nrows + WAVES_PER_BLOCK - 1) / WAVES_PER_BLOCK;

    entmax15_kernel<<<grid, 256, 0, stream>>>(scores, mask, out, nrows);
}

// Round 5
// 587.245 us; speedup vs baseline: 1.0026x; 1.0026x over previous
//
#include <hip/hip_runtime.h>

// Entmax-1.5 over last axis. tau* is the root of
//   f(tau) = sum_i max(x_i - tau, 0)^2 - 1   (convex, piecewise quadratic, decreasing)
// Piece-exact (Michelot-style) iteration with F = sum y^2, G = sum y, K = #{y>0}:
//   u = (F-1) / (G + sqrt(G^2 - K*(F-1))),  tau += u
// Exit when support size K repeats (exact small integer in fp32 -> noise-free).
//
// R4: ALL wave reductions via DPP (rocPRIM wave64 pattern: row_shr 1/2/4/8 +
// row_bcast15/31, total lands in lane 63, readlane broadcasts via SGPR).
// Rationale: __shfl_xor lowers to ds_bpermute_b32 (~100+ cyc, lgkmcnt wait,
// shared per-CU DS pipe). R0-R3 all pinned at ~195 us with VALU work varying
// 2x -> latency-bound on the butterfly chains (~6 dependent bpermute levels
// x ~8 iterations per wave). DPP reduce is ~25-60 cyc per value, VALU-only.
// One wave per row of S=2048; 32 elems/lane in registers; no LDS.

#define NEG_FILL (-1.0e4f)

static constexpr int S_DIM = 2048;
static constexpr int WAVES_PER_BLOCK = 4;       // 256-thread blocks
static constexpr int ELEMS = S_DIM / 64;        // 32 floats per lane
static constexpr int VEC = ELEMS / 4;           // 8 float4 loads per lane

template<int CTRL, int ROW_MASK, int BANK_MASK>
__device__ __forceinline__ float dpp_mov(float x, float old) {
    return __int_as_float(__builtin_amdgcn_update_dpp(
        __float_as_int(old), __float_as_int(x), CTRL, ROW_MASK, BANK_MASK, false));
}

// rocPRIM wave64 sum: prefix within rows, then cross-row bcasts; total in lane 63.
__device__ __forceinline__ float wave_sum_bcast(float x) {
    x += dpp_mov<0x111, 0xf, 0xf>(x, 0.0f);   // row_shr:1
    x += dpp_mov<0x112, 0xf, 0xf>(x, 0.0f);   // row_shr:2
    x += dpp_mov<0x114, 0xf, 0xe>(x, 0.0f);   // row_shr:4
    x += dpp_mov<0x118, 0xf, 0xc>(x, 0.0f);   // row_shr:8
    x += dpp_mov<0x142, 0xa, 0xf>(x, 0.0f);   // row_bcast:15 -> rows 1,3
    x += dpp_mov<0x143, 0xc, 0xf>(x, 0.0f);   // row_bcast:31 -> rows 2,3
    return __int_as_float(__builtin_amdgcn_readlane(__float_as_int(x), 63));
}

__device__ __forceinline__ float wave_max_bcast(float x) {
    // old = x is the identity for max on masked/invalid lanes
    x = fmaxf(x, dpp_mov<0x111, 0xf, 0xf>(x, x));
    x = fmaxf(x, dpp_mov<0x112, 0xf, 0xf>(x, x));
    x = fmaxf(x, dpp_mov<0x114, 0xf, 0xe>(x, x));
    x = fmaxf(x, dpp_mov<0x118, 0xf, 0xc>(x, x));
    x = fmaxf(x, dpp_mov<0x142, 0xa, 0xf>(x, x));
    x = fmaxf(x, dpp_mov<0x143, 0xc, 0xf>(x, x));
    return __int_as_float(__builtin_amdgcn_readlane(__float_as_int(x), 63));
}

__global__ __launch_bounds__(256) void entmax15_kernel(
    const float* __restrict__ scores,
    const int*   __restrict__ mask,
    float*       __restrict__ out,
    int nrows)
{
    const int lane = threadIdx.x & 63;
    const int wave = threadIdx.x >> 6;
    const int row  = blockIdx.x * WAVES_PER_BLOCK + wave;
    if (row >= nrows) return;

    const size_t base = (size_t)row * S_DIM;
    const float4* __restrict__ srow = (const float4*)(scores + base);
    const int4*   __restrict__ mrow = (const int4*)(mask + base);
    float4*       __restrict__ orow = (float4*)(out + base);

    // ---- load + mask + row max (in registers) ----
    float x[ELEMS];
    float rmax = -3.402823466e38f;
#pragma unroll
    for (int j = 0; j < VEC; ++j) {
        const float4 s = srow[lane + 64 * j];
        const int4   m = mrow[lane + 64 * j];
        float v0 = m.x ? s.x : NEG_FILL;
        float v1 = m.y ? s.y : NEG_FILL;
        float v2 = m.z ? s.z : NEG_FILL;
        float v3 = m.w ? s.w : NEG_FILL;
        x[4 * j + 0] = v0;
        x[4 * j + 1] = v1;
        x[4 * j + 2] = v2;
        x[4 * j + 3] = v3;
        rmax = fmaxf(rmax, fmaxf(fmaxf(v0, v1), fmaxf(v2, v3)));
    }
    rmax = wave_max_bcast(rmax);

    // ---- alpha=1.5 transform: x = (x - max) * 0.5  => max(x) == 0, tau* in [-1, 0) ----
    const float shift = -0.5f * rmax;
#pragma unroll
    for (int i = 0; i < ELEMS; ++i)
        x[i] = fmaf(0.5f, x[i], shift);

    // ---- piece-exact root iteration from tau0 = -1 ----
    float tau = -1.0f;
    float Kprev = -1.0f;   // sentinel; K >= 1 always (max elem is 0 > tau)
#pragma unroll 1
    for (int it = 0; it < 12; ++it) {
        float F = 0.0f, G = 0.0f, K = 0.0f;
#pragma unroll
        for (int i = 0; i < ELEMS; ++i) {
            float d = x[i] - tau;
            float y = fmaxf(d, 0.0f);
            F = fmaf(y, y, F);
            G += y;
            K += (d > 0.0f) ? 1.0f : 0.0f;
        }
        // three independent DPP chains -> hazards overlap
        F = wave_sum_bcast(F);
        G = wave_sum_bcast(G);
        K = wave_sum_bcast(K);
        // Support stabilized => previous update solved the final piece exactly.
        if (K == Kprev) break;
        Kprev = K;

        const float c = F - 1.0f;
        const float disc = fmaf(G, G, -K * c);
        // disc>0: exact in-piece root; else Newton fallback (from-below safe)
        const float denom = (disc > 0.0f) ? (G + sqrtf(disc)) : (2.0f * G);
        const float u = c / denom;
        tau += u;
        if (!(fabsf(u) > 1e-6f)) break;   // backup exit (e.g. exact root hit)
    }

    // ---- epilogue: p = max(x - tau, 0)^2, coalesced float4 stores ----
#pragma unroll
    for (int j = 0; j < VEC; ++j) {
        float y0 = fmaxf(x[4 * j + 0] - tau, 0.0f);
        float y1 = fmaxf(x[4 * j + 1] - tau, 0.0f);
        float y2 = fmaxf(x[4 * j + 2] - tau, 0.0f);
        float y3 = fmaxf(x[4 * j + 3] - tau, 0.0f);
        float4 o;
        o.x = y0 * y0;
        o.y = y1 * y1;
        o.z = y2 * y2;
        o.w = y3 * y3;
        orow[lane + 64 * j] = o;
    }
}

extern "C" void kernel_launch(void* const* d_in, const int* in_sizes, int n_in,
                              void* d_out, int out_size, void* d_ws, size_t ws_size,
                              hipStream_t stream) {
    const float* scores = (const float*)d_in[0];
    const int*   mask   = (const int*)d_in[1];
    float*       out    = (float*)d_out;

    const int nrows = in_sizes[0] / S_DIM;  // 32768
    const int grid  = (nrows + WAVES_PER_BLOCK - 1) / WAVES_PER_BLOCK;

    entmax15_kernel<<<grid, 256, 0, stream>>>(scores, mask, out, nrows);
}